// Round 1
// baseline (68.998 us; speedup 1.0000x reference)
//
#include <hip/hip_runtime.h>
#include <math.h>

#define KS   35
#define PAD  17
#define H    128
#define W    128
#define NC   3
#define TILE 8
#define LW   (TILE + KS - 1)   // 42
#define BLK  256

__device__ __forceinline__ int reflect_idx(int p) {
    // jnp.pad mode='reflect' (no edge repeat); pad=17 < H so one reflection suffices
    if (p < 0) p = -p;
    if (p >= H) p = 2 * H - 2 - p;
    return p;
}

__global__ __launch_bounds__(BLK)
void bilateral_kernel(const float* __restrict__ x, float* __restrict__ out) {
    __shared__ float s_in[NC][LW][LW];  // 21168 B
    __shared__ float s_g[KS * KS];      // 4900 B

    const int tid = threadIdx.x;
    const int tx0 = blockIdx.x * TILE;
    const int ty0 = blockIdx.y * TILE;

    const float sigma  = 5.6f;               // 0.3*((35-1)*0.5-1)+0.8
    const float inv2s2 = 1.0f / (2.0f * sigma * sigma);

    // stage unnormalized spatial gaussian (normalization cancels in out)
    for (int k = tid; k < KS * KS; k += BLK) {
        int di = k / KS, dj = k - di * KS;
        float r2 = (float)((di - PAD) * (di - PAD) + (dj - PAD) * (dj - PAD));
        s_g[k] = __expf(-r2 * inv2s2);
    }
    // stage input tile with reflect padding resolved once
    for (int idx = tid; idx < NC * LW * LW; idx += BLK) {
        int c   = idx / (LW * LW);
        int rem = idx - c * (LW * LW);
        int ly  = rem / LW, lx = rem - ly * LW;
        int gy  = reflect_idx(ty0 - PAD + ly);
        int gx  = reflect_idx(tx0 - PAD + lx);
        (&s_in[0][0][0])[idx] = x[(c * H + gy) * W + gx];
    }
    __syncthreads();

    // 4 threads per pixel: sub handles di rows with di % 4 == sub
    const int sub = tid & 3;
    const int pix = tid >> 2;            // 0..63
    const int py  = pix >> 3, px = pix & 7;

    const float c0 = s_in[0][py + PAD][px + PAD];
    const float c1 = s_in[1][py + PAD][px + PAD];
    const float c2 = s_in[2][py + PAD][px + PAD];

    float n0 = 0.f, n1 = 0.f, n2 = 0.f, den = 0.f;
    for (int di = sub; di < KS; di += 4) {
        const float* r0 = &s_in[0][py + di][px];
        const float* r1 = &s_in[1][py + di][px];
        const float* r2 = &s_in[2][py + di][px];
        const float* gw = &s_g[di * KS];
        #pragma unroll 5
        for (int dj = 0; dj < KS; ++dj) {
            float p0 = r0[dj], p1 = r1[dj], p2 = r2[dj];
            float dd = (fabsf(p0 - c0) + fabsf(p1 - c1) + fabsf(p2 - c2)) * (1.0f / 3.0f);
            float wd = __expf(-dd * dd * inv2s2);
            float w  = wd * gw[dj];
            n0 = fmaf(w, p0, n0);
            n1 = fmaf(w, p1, n1);
            n2 = fmaf(w, p2, n2);
            den += w;
        }
    }

    // reduce across the 4 sub-lanes (lane-contiguous within a wave)
    for (int m = 1; m <= 2; m <<= 1) {
        n0  += __shfl_xor(n0, m);
        n1  += __shfl_xor(n1, m);
        n2  += __shfl_xor(n2, m);
        den += __shfl_xor(den, m);
    }

    if (sub == 0) {
        int gy = ty0 + py, gx = tx0 + px;
        float inv = 1.0f / den;
        out[(0 * H + gy) * W + gx] = n0 * inv;
        out[(1 * H + gy) * W + gx] = n1 * inv;
        out[(2 * H + gy) * W + gx] = n2 * inv;
    }
}

extern "C" void kernel_launch(void* const* d_in, const int* in_sizes, int n_in,
                              void* d_out, int out_size, void* d_ws, size_t ws_size,
                              hipStream_t stream) {
    const float* x = (const float*)d_in[0];
    float* out = (float*)d_out;
    dim3 grid(W / TILE, H / TILE);   // 16 x 16 = 256 blocks
    dim3 block(BLK);
    bilateral_kernel<<<grid, block, 0, stream>>>(x, out);
}

// Round 2
// 64.680 us; speedup vs baseline: 1.0668x; 1.0668x over previous
//
#include <hip/hip_runtime.h>
#include <math.h>

#define KS   35
#define PAD  17
#define H    128
#define W    128
#define TILE 4
#define LW   (TILE + KS - 1)   // 38
#define BLK  256

struct alignas(16) F4 { float c0, c1, c2, pd; };

__device__ __forceinline__ int reflect_idx(int p) {
    // jnp.pad mode='reflect'; pad=17 < H so one reflection suffices
    if (p < 0) p = -p;
    if (p >= H) p = 2 * H - 2 - p;
    return p;
}

__global__ __launch_bounds__(BLK, 4)
void bilateral_kernel(const float* __restrict__ x, float* __restrict__ out) {
    __shared__ F4 s_in[LW * LW];   // 38*38*16 = 23104 B, channel-interleaved

    const int tid = threadIdx.x;
    const int tx0 = blockIdx.x * TILE;
    const int ty0 = blockIdx.y * TILE;

    // sigma = 0.3*((35-1)*0.5-1)+0.8 = 5.6 exactly
    const float LOG2E = 1.4426950408889634f;
    const float c_sp  = LOG2E / 62.72f;          // log2-domain spatial coeff (2*sigma^2 = 62.72)
    const float c_rng = LOG2E / (62.72f * 9.0f); // range coeff, /9 folds the mean's 1/3

    // stage input tile: reflect resolved once, channels interleaved -> b128 reads
    for (int idx = tid; idx < LW * LW; idx += BLK) {
        int ly = idx / LW, lx = idx - ly * LW;
        int gy = reflect_idx(ty0 - PAD + ly);
        int gx = reflect_idx(tx0 - PAD + lx);
        F4 v;
        v.c0 = x[gy * W + gx];
        v.c1 = x[H * W + gy * W + gx];
        v.c2 = x[2 * H * W + gy * W + gx];
        v.pd = 0.0f;
        s_in[idx] = v;
    }
    __syncthreads();

    // 16 threads per pixel: si strides di by 4, sj strides dj by 4
    const int sub = tid & 15;
    const int pix = tid >> 4;        // 0..15
    const int px  = pix & 3, py = pix >> 2;
    const int si  = sub & 3, sj = sub >> 2;

    const F4 c = s_in[(py + PAD) * LW + (px + PAD)];

    // log2-domain spatial gaussian via second-difference recurrences:
    // g(di,dj) = -c_sp*((di-17)^2 + (dj-17)^2), strides of 4 in both dims
    float a   = -c_sp * (float)((si - PAD) * (si - PAD));
    float ad  = -c_sp * (float)(8 * (si - PAD) + 16);
    const float b0   = -c_sp * (float)((sj - PAD) * (sj - PAD));
    const float bd0  = -c_sp * (float)(8 * (sj - PAD) + 16);
    const float add2 = -32.0f * c_sp;

    float n0 = 0.f, n1 = 0.f, n2 = 0.f, den = 0.f;
    for (int di = si; di < KS; di += 4) {
        const F4* row = &s_in[(py + di) * LW + px];
        float g  = a + b0;
        float gd = bd0;
        for (int dj = sj; dj < KS; dj += 4) {
            F4 p = row[dj];
            float s = fabsf(p.c0 - c.c0) + fabsf(p.c1 - c.c1) + fabsf(p.c2 - c.c2);
            float w = __builtin_amdgcn_exp2f(fmaf(s * s, -c_rng, g));
            n0 = fmaf(w, p.c0, n0);
            n1 = fmaf(w, p.c1, n1);
            n2 = fmaf(w, p.c2, n2);
            den += w;
            g += gd; gd += add2;
        }
        a += ad; ad += add2;
    }

    // reduce across the 16 sub-lanes (lane-contiguous)
    for (int m = 1; m <= 8; m <<= 1) {
        n0  += __shfl_xor(n0, m);
        n1  += __shfl_xor(n1, m);
        n2  += __shfl_xor(n2, m);
        den += __shfl_xor(den, m);
    }

    if (sub == 0) {
        int gy = ty0 + py, gx = tx0 + px;
        float inv = 1.0f / den;
        out[(0 * H + gy) * W + gx] = n0 * inv;
        out[(1 * H + gy) * W + gx] = n1 * inv;
        out[(2 * H + gy) * W + gx] = n2 * inv;
    }
}

extern "C" void kernel_launch(void* const* d_in, const int* in_sizes, int n_in,
                              void* d_out, int out_size, void* d_ws, size_t ws_size,
                              hipStream_t stream) {
    const float* x = (const float*)d_in[0];
    float* out = (float*)d_out;
    dim3 grid(W / TILE, H / TILE);   // 32 x 32 = 1024 blocks -> 4 blocks/CU
    dim3 block(BLK);
    bilateral_kernel<<<grid, block, 0, stream>>>(x, out);
}

// Round 3
// 64.183 us; speedup vs baseline: 1.0750x; 1.0077x over previous
//
#include <hip/hip_runtime.h>
#include <math.h>

#define KS   35
#define PAD  17
#define H    128
#define W    128
#define TLX  16          // pixels per block, x
#define TLY  2           // pixels per block, y
#define TW   51          // tile width : qr(<=3)+sj(<=3)+4*11(=44) -> 50, +1
#define TH   41          // tile height: qy(<=1)+di(<=39) -> 40, +1
#define BLK  256

struct alignas(16) F4 { float c0, c1, c2, pd; };

__device__ __forceinline__ int reflect_idx(int p) {
    // jnp.pad mode='reflect'; max overhang 33 < H so one reflection suffices
    if (p < 0) p = -p;
    if (p >= H) p = 2 * H - 2 - p;
    return p;
}

__global__ __launch_bounds__(BLK, 2)
void bilateral_kernel(const float* __restrict__ x, float* __restrict__ out) {
    __shared__ F4 s_in[TH * TW];   // 2091 * 16 = 33456 B -> 2 blocks/CU

    const int tid = threadIdx.x;
    const int tx0 = blockIdx.x * TLX;
    const int ty0 = blockIdx.y * TLY;

    // sigma = 5.6 exactly; 2*sigma^2 = 62.72. log2-domain weights; the
    // wd- and G-normalizations cancel in out = sum(w p)/sum(w).
    const float LOG2E  = 1.4426950408889634f;
    const float c_sp   = LOG2E / 62.72f;           // spatial coeff
    const float c_rng  = LOG2E / (62.72f * 9.0f);  // range coeff, /9 folds mean's 1/3
    const float NEGBIG = -1.0e30f;                 // exp2 -> 0 : kills padded taps

    // stage tile: reflect resolved once, channels interleaved -> b128 reads
    for (int idx = tid; idx < TH * TW; idx += BLK) {
        int ly = idx / TW, lx = idx - ly * TW;
        int gy = reflect_idx(ty0 - PAD + ly);
        int gx = reflect_idx(tx0 - PAD + lx);
        F4 v;
        v.c0 = x[gy * W + gx];
        v.c1 = x[H * W + gy * W + gx];
        v.c2 = x[2 * H * W + gy * W + gx];
        v.pd = 0.0f;
        s_in[idx] = v;
    }
    __syncthreads();

    // thread -> (quad, si, sj): quad picks (row qy, x-residue qr);
    // thread owns 4 pixels x = qr + 4p, taps di=si+8t (rows padded to 40),
    // dj=sj+4j (cols padded to 36). 32 lanes (sub) reduce per pixel-group.
    const int sub  = tid & 31;
    const int si   = sub >> 2;       // 0..7
    const int sj   = sub & 3;        // 0..3
    const int quad = tid >> 5;       // 0..7
    const int qy   = quad >> 2;      // 0..1
    const int qr   = quad & 3;       // 0..3

    // centers for the 4 pixels
    F4 c[4];
    #pragma unroll
    for (int p = 0; p < 4; ++p)
        c[p] = s_in[(qy + PAD) * TW + (qr + 4 * p + PAD)];

    // column log2-gaussian terms; dj=35 is padding -> -inf
    float b[9];
    #pragma unroll
    for (int j = 0; j < 9; ++j) {
        int dj = sj + 4 * j;
        float fd = (float)(dj - PAD);
        b[j] = (dj <= 34) ? (-c_sp * fd * fd) : NEGBIG;
    }

    float a0[4] = {0.f, 0.f, 0.f, 0.f};
    float a1[4] = {0.f, 0.f, 0.f, 0.f};
    float a2[4] = {0.f, 0.f, 0.f, 0.f};
    float ad[4] = {0.f, 0.f, 0.f, 0.f};

    #pragma unroll
    for (int t = 0; t < 5; ++t) {
        const int di = si + 8 * t;                 // <= 39 (35..39 padded)
        float fdi = (float)(di - PAD);
        float a = (di <= 34) ? (-c_sp * fdi * fdi) : NEGBIG;

        const F4* row = &s_in[(qy + di) * TW + (qr + sj)];
        F4 v[12];
        #pragma unroll
        for (int k = 0; k < 12; ++k) v[k] = row[4 * k];

        float ab[9];
        #pragma unroll
        for (int j = 0; j < 9; ++j) ab[j] = a + b[j];

        #pragma unroll
        for (int p = 0; p < 4; ++p) {
            #pragma unroll
            for (int j = 0; j < 9; ++j) {
                F4 q = v[p + j];                   // read shared by 4 pixels
                float s = fabsf(q.c0 - c[p].c0) + fabsf(q.c1 - c[p].c1)
                        + fabsf(q.c2 - c[p].c2);
                float w = __builtin_amdgcn_exp2f(fmaf(s * s, -c_rng, ab[j]));
                a0[p] = fmaf(w, q.c0, a0[p]);
                a1[p] = fmaf(w, q.c1, a1[p]);
                a2[p] = fmaf(w, q.c2, a2[p]);
                ad[p] += w;
            }
        }
    }

    // reduce across the 32 sub-lanes (lane-contiguous within the wave)
    #pragma unroll
    for (int m = 1; m <= 16; m <<= 1) {
        #pragma unroll
        for (int p = 0; p < 4; ++p) {
            a0[p] += __shfl_xor(a0[p], m);
            a1[p] += __shfl_xor(a1[p], m);
            a2[p] += __shfl_xor(a2[p], m);
            ad[p] += __shfl_xor(ad[p], m);
        }
    }

    if (sub == 0) {
        int gy = ty0 + qy;
        #pragma unroll
        for (int p = 0; p < 4; ++p) {
            int gx = tx0 + qr + 4 * p;
            float inv = 1.0f / ad[p];
            out[(0 * H + gy) * W + gx] = a0[p] * inv;
            out[(1 * H + gy) * W + gx] = a1[p] * inv;
            out[(2 * H + gy) * W + gx] = a2[p] * inv;
        }
    }
}

extern "C" void kernel_launch(void* const* d_in, const int* in_sizes, int n_in,
                              void* d_out, int out_size, void* d_ws, size_t ws_size,
                              hipStream_t stream) {
    const float* x = (const float*)d_in[0];
    float* out = (float*)d_out;
    dim3 grid(W / TLX, H / TLY);   // 8 x 64 = 512 blocks -> 2 blocks/CU
    dim3 block(BLK);
    bilateral_kernel<<<grid, block, 0, stream>>>(x, out);
}